// Round 14
// baseline (396.587 us; speedup 1.0000x reference)
//
#include <hip/hip_runtime.h>
#include <hip/hip_bf16.h>
#include <stdint.h>

// Problem constants (Attention_21552145891894): B=64, S=1024, DEC=ENC=ATTN=1024
#define NB 64
#define NS 1024
#define NE 1024   // ENC (= K of big GEMM)
#define NA 1024   // ATTN (= N of big GEMM)
#define NF 2048   // DEC+ENC (W_attn row length)
#define LDP 144   // padded LDS row stride (fallback reg-staged kernel only)

typedef __attribute__((ext_vector_type(8))) short   short8;
typedef __attribute__((ext_vector_type(4))) short   short4v;
typedef __attribute__((ext_vector_type(4))) float   f32x4;
typedef __attribute__((ext_vector_type(8))) __bf16  bf16x8;

__device__ __forceinline__ unsigned short f2bf(float x) {
  union { float f; unsigned u; } v; v.f = x;
  unsigned r = v.u + 0x7fffu + ((v.u >> 16) & 1u);   // RNE
  return (unsigned short)(r >> 16);
}
__device__ __forceinline__ float bf2f(unsigned short h) {
  union { unsigned u; float f; } v; v.u = ((unsigned)h) << 16;
  return v.f;
}
__device__ __forceinline__ float tanh_fast(float x) {
  float e = __expf(2.0f * x);                        // overflow -> inf -> 1; underflow -> -1
  return 1.0f - __fdividef(2.0f, e + 1.0f);
}
__device__ __forceinline__ short8 pack8(float4 a, float4 b) {
  short8 h;
  h[0]=(short)f2bf(a.x); h[1]=(short)f2bf(a.y); h[2]=(short)f2bf(a.z); h[3]=(short)f2bf(a.w);
  h[4]=(short)f2bf(b.x); h[5]=(short)f2bf(b.y); h[6]=(short)f2bf(b.z); h[7]=(short)f2bf(b.w);
  return h;
}
__device__ __forceinline__ void gload_lds16(const void* g, void* l) {
  // HW: LDS dest is wave-uniform base + lane*16; size must be literal 16 (m97/m104)
  __builtin_amdgcn_global_load_lds((const __attribute__((address_space(1))) void*)g,
                                   (__attribute__((address_space(3))) void*)l, 16, 0, 0);
}

// ---------------- zero scratch (scores + ctx), deterministic each call ----------------
__global__ __launch_bounds__(256) void k_zero(float4* __restrict__ p, int n4) {
  int i = blockIdx.x * 256 + threadIdx.x;
  if (i < n4) { float4 z; z.x = z.y = z.z = z.w = 0.f; p[i] = z; }
}

// ---------------- W_enc (= W_attn[:,1024:2048]) f32 -> bf16 [1024][1024] ----------------
__global__ __launch_bounds__(256) void k_conv_w(const float* __restrict__ W, short8* __restrict__ dst) {
  const int id = blockIdx.x * 256 + threadIdx.x;   // 131072 total
  const int a = id >> 7, ku = id & 127;
  const float* s = W + (size_t)a * NF + 1024 + ku * 8;
  float4 x = *(const float4*)s;
  float4 y = *(const float4*)(s + 4);
  dst[id] = pack8(x, y);
}

// ---------------- u[b,a] = hidden[b] . W_attn[a,0:1024] + b_attn[a]  (fp32 exact) ----------------
__global__ __launch_bounds__(256) void k_u(const float* __restrict__ hidden,
                                           const float* __restrict__ W,
                                           const float* __restrict__ bias,
                                           float* __restrict__ u) {
  const int l = threadIdx.x & 63;
  const int w = threadIdx.x >> 6;
  const int a = (blockIdx.x >> 1) * 4 + w;         // grid 512 -> a in [0,1024)
  const int bh = blockIdx.x & 1;
  const float* wrow = W + (size_t)a * NF;          // dec half: cols 0..1023
  float4 wv[4];
  #pragma unroll
  for (int i = 0; i < 4; ++i) wv[i] = *(const float4*)(wrow + l * 4 + i * 256);
  const float ba = bias[a];
  for (int b = bh * 32; b < bh * 32 + 32; ++b) {
    const float* hrow = hidden + b * 1024;
    float s = 0.f;
    #pragma unroll
    for (int i = 0; i < 4; ++i) {
      float4 hv = *(const float4*)(hrow + l * 4 + i * 256);
      s += wv[i].x * hv.x + wv[i].y * hv.y + wv[i].z * hv.z + wv[i].w * hv.w;
    }
    #pragma unroll
    for (int m = 1; m < 64; m <<= 1) s += __shfl_xor(s, m);
    if (l == 0) u[b * NA + a] = s + ba;
  }
}

// ======== main fused GEMM (tier0): 256x256 dbuf (r7 macro-schedule) + FUSED enc conversion ========
// r7 (193us, best of 6 schedule variants) with k_conv_enc (~70us, 384MB) folded in:
//  - A (enc) is reg-staged with in-flight f32->bf16 pack (T14 split: float4 loads at
//    step top, pack+swizzled ds_write after the MFMA cluster). ds_write dest swizzle
//    = same k-unit involution as r5 (write-side applied directly; 2-way bank alias = free).
//  - B (Wb) keeps r7's verified gload_lds staging (pre-swizzled source).
//  - ct==0 block stores its packed A-panel to encb (each panel written exactly once)
//    so k_ctx keeps the cheap bf16 read. Same RNE pack as the old conv kernel.
//  - One __syncthreads per K-step (vm+lgkm drain: all t+1 traffic aged a full step).
// Same accumulation order as r7 -> absmax must be exactly 0.05078125.
__global__ __launch_bounds__(512, 2) void k_main256f(const float* __restrict__ encf,
                                                     const unsigned short* __restrict__ Wb,
                                                     const float* __restrict__ u_,
                                                     const float* __restrict__ v_,
                                                     float* __restrict__ scores,
                                                     unsigned short* __restrict__ encb) {
  __shared__ __align__(16) char smem[2 * 65536];   // buf k: A 32KB @k*65536, B 32KB @+32768

  const int tid = threadIdx.x;
  const int l = tid & 63;
  const int w = tid >> 6;                   // 0..7
  const int wr = w >> 2, wc = w & 3;        // 2M x 4N wave grid
  const int d = blockIdx.x;
  const int xcd = d & 7, q = d >> 3;
  const int rt = xcd * 32 + (q >> 2);       // row tile [0,256)
  const int ct = q & 3;                     // col tile [0,4)
  const int b = rt >> 2;                    // batch (256-row tiles never straddle)
  const int lh = l >> 4, l15 = l & 15, l7 = l & 7;

  // A reg-staging: thread -> row (tid>>3) in each 64-row group, LINEAR k-unit (tid&7).
  const int arow = tid >> 3, aku = tid & 7;
  const float* aF = encf + (size_t)(rt * 256 + arow) * NE + aku * 8;   // 8 f32 = 32B
  unsigned short* aO = encb + (size_t)(rt * 256 + arow) * NE + aku * 8;
  const int awdst = arow * 128 + ((aku ^ (arow & 7)) << 4);            // swizzled LDS dest

  // B staging (r7): pre-swizzled source, wave-uniform dest
  const int ssk = ((tid & 7) ^ ((tid >> 3) & 7)) * 8;
  const unsigned short* bS = Wb + (size_t)(ct * 256 + (tid >> 3)) * NE + ssk;
  const int wdstB = w * 1024;

  f32x4 acc[8][4] = {};

#define STG_B(dst_, tt) do { \
    const unsigned short* b_ = bS + (size_t)(tt) * 64; \
    gload_lds16(b_,                    (dst_) + 32768 + wdstB); \
    gload_lds16(b_ + (size_t) 64 * NE, (dst_) + 32768 +  64 * 128 + wdstB); \
    gload_lds16(b_ + (size_t)128 * NE, (dst_) + 32768 + 128 * 128 + wdstB); \
    gload_lds16(b_ + (size_t)192 * NE, (dst_) + 32768 + 192 * 128 + wdstB); } while (0)

  // ---- prologue: stage tile 0 (A reg-convert + B gloads) into buf 0 ----
  {
    #pragma unroll
    for (int g = 0; g < 4; ++g) {
      float4 x = *(const float4*)(aF + (size_t)g * 64 * NE);
      float4 y = *(const float4*)(aF + (size_t)g * 64 * NE + 4);
      short8 pv = pack8(x, y);
      *(short8*)(smem + g * 64 * 128 + awdst) = pv;
      if (ct == 0) *(short8*)(aO + (size_t)g * 64 * NE) = pv;   // encb chunk 0
    }
    STG_B(smem, 0);
  }

  for (int t = 0; t < 16; ++t) {
    __syncthreads();                        // drains vm+lgkm (all aged >= 1 step) + barrier

    const char* As = smem + ((t & 1) << 16);
    const char* Bs = As + 32768;
    char* Nx = smem + (((t + 1) & 1) << 16);

    // ---- issue next tile's traffic first (T14: loads age across the MFMA cluster) ----
    float4 ax[4][2];
    if (t < 15) {
      const float* af = aF + (t + 1) * 64;
      #pragma unroll
      for (int g = 0; g < 4; ++g) {
        ax[g][0] = *(const float4*)(af + (size_t)g * 64 * NE);
        ax[g][1] = *(const float4*)(af + (size_t)g * 64 * NE + 4);
      }
      STG_B(Nx, t + 1);
    }

    // ---- A/B fragments from LDS (swizzled reads, conflict-free r5-verified) ----
    bf16x8 areg[8][2], breg[4][2];
    #pragma unroll
    for (int rf = 0; rf < 8; ++rf)
      #pragma unroll
      for (int kh = 0; kh < 2; ++kh)
        areg[rf][kh] = *(const bf16x8*)(As + (wr * 128 + rf * 16 + l15) * 128
                                           + (((kh * 4 + lh) ^ l7) << 4));
    #pragma unroll
    for (int cf = 0; cf < 4; ++cf)
      #pragma unroll
      for (int kh = 0; kh < 2; ++kh)
        breg[cf][kh] = *(const bf16x8*)(Bs + (wc * 64 + cf * 16 + l15) * 128
                                           + (((kh * 4 + lh) ^ l7) << 4));

    __builtin_amdgcn_s_setprio(1);
    #pragma unroll
    for (int rf = 0; rf < 8; ++rf)
      #pragma unroll
      for (int cf = 0; cf < 4; ++cf)
        #pragma unroll
        for (int kh = 0; kh < 2; ++kh)
          acc[rf][cf] = __builtin_amdgcn_mfma_f32_16x16x32_bf16(areg[rf][kh], breg[cf][kh], acc[rf][cf], 0, 0, 0);
    __builtin_amdgcn_s_setprio(0);

    // ---- pack + swizzled ds_write of A(t+1); ct==0 also persists bf16 panel ----
    if (t < 15) {
      #pragma unroll
      for (int g = 0; g < 4; ++g) {
        short8 pv = pack8(ax[g][0], ax[g][1]);
        *(short8*)(Nx + g * 64 * 128 + awdst) = pv;
        if (ct == 0) *(short8*)(aO + (size_t)g * 64 * NE + (t + 1) * 64) = pv;
      }
    }
  }
#undef STG_B

  // ---- epilogue: D frag col=l&15, row=(l>>4)*4+reg (m89-verified) ----
  const int colb = ct * 256 + wc * 64 + l15;
  float uv[4], vv[4];
  #pragma unroll
  for (int cf = 0; cf < 4; ++cf) {
    const int c = colb + cf * 16;
    uv[cf] = u_[b * NA + c];
    vv[cf] = v_[c];
  }
  #pragma unroll
  for (int rf = 0; rf < 8; ++rf) {
    #pragma unroll
    for (int reg = 0; reg < 4; ++reg) {
      float sacc = 0.f;
      #pragma unroll
      for (int cf = 0; cf < 4; ++cf)
        sacc += tanh_fast(acc[rf][cf][reg] + uv[cf]) * vv[cf];
      sacc += __shfl_xor(sacc, 1);
      sacc += __shfl_xor(sacc, 2);
      sacc += __shfl_xor(sacc, 4);
      sacc += __shfl_xor(sacc, 8);
      if (l15 == 0) {
        const int m = rt * 256 + wr * 128 + rf * 16 + lh * 4 + reg;
        atomicAdd(&scores[m], sacc);         // 16 partials per row (4 ct x 4 wc)
      }
    }
  }
}

// ======== fallback (small ws): reg-staged padded-LDS version (round-3-verified) ========
template <int ACONV, int BCONV>
__global__ __launch_bounds__(256) void k_main_rs(const void* __restrict__ Asrc,
                                                 const void* __restrict__ Bsrc,
                                                 const float* __restrict__ u_,
                                                 const float* __restrict__ v_,
                                                 float* __restrict__ scores) {
  __shared__ __align__(16) char smemf[2 * 128 * LDP];
  char* As = smemf;
  char* Bs = smemf + 128 * LDP;
  const int tid = threadIdx.x;
  const int l = tid & 63;
  const int w = tid >> 6;
  const int wr = w >> 1, wc = w & 1;
  const int d = blockIdx.x;
  const int rt = (d & 7) * 64 + (d >> 6);
  const int ct = (d >> 3) & 7;
  const int b = rt >> 3;
  const int l7 = l & 7, lh = l >> 4, l15 = l & 15;
  const int srow = w * 8 + (l >> 3);
  f32x4 acc[4][4] = {};
  for (int kt = 0; kt < 16; ++kt) {
    const int k0 = kt * 64;
    __syncthreads();
    #pragma unroll
    for (int r = 0; r < 4; ++r) {
      const int row = r * 32 + srow;
      short8 val;
      if constexpr (ACONV) {
        const float* s = (const float*)Asrc + (size_t)(rt * 128 + row) * NE + k0 + l7 * 8;
        val = pack8(*(const float4*)s, *(const float4*)(s + 4));
      } else {
        val = *(const short8*)((const unsigned short*)Asrc + (size_t)(rt * 128 + row) * NE + k0 + l7 * 8);
      }
      *(short8*)(As + row * LDP + l7 * 16) = val;
    }
    #pragma unroll
    for (int r = 0; r < 4; ++r) {
      const int row = r * 32 + srow;
      short8 val;
      if constexpr (BCONV) {
        const float* s = (const float*)Bsrc + (size_t)(ct * 128 + row) * NF + 1024 + k0 + l7 * 8;
        val = pack8(*(const float4*)s, *(const float4*)(s + 4));
      } else {
        val = *(const short8*)((const unsigned short*)Bsrc + (size_t)(ct * 128 + row) * NE + k0 + l7 * 8);
      }
      *(short8*)(Bs + row * LDP + l7 * 16) = val;
    }
    __syncthreads();
    #pragma unroll
    for (int ks = 0; ks < 2; ++ks) {
      bf16x8 af[4], bfr[4];
      const int ku = (ks * 4 + lh) * 16;
      #pragma unroll
      for (int f = 0; f < 4; ++f) {
        af[f]  = *(const bf16x8*)(As + (wr * 64 + f * 16 + l15) * LDP + ku);
        bfr[f] = *(const bf16x8*)(Bs + (wc * 64 + f * 16 + l15) * LDP + ku);
      }
      #pragma unroll
      for (int i = 0; i < 4; ++i)
        #pragma unroll
        for (int jj = 0; jj < 4; ++jj)
          acc[i][jj] = __builtin_amdgcn_mfma_f32_16x16x32_bf16(af[i], bfr[jj], acc[i][jj], 0, 0, 0);
    }
  }
  const int colb = ct * 128 + wc * 64 + l15;
  float uv[4], vv[4];
  #pragma unroll
  for (int jj = 0; jj < 4; ++jj) {
    const int c = colb + jj * 16;
    uv[jj] = u_[b * NA + c];
    vv[jj] = v_[c];
  }
  #pragma unroll
  for (int i = 0; i < 4; ++i) {
    #pragma unroll
    for (int reg = 0; reg < 4; ++reg) {
      float sacc = 0.f;
      #pragma unroll
      for (int jj = 0; jj < 4; ++jj)
        sacc += tanh_fast(acc[i][jj][reg] + uv[jj]) * vv[jj];
      sacc += __shfl_xor(sacc, 1);
      sacc += __shfl_xor(sacc, 2);
      sacc += __shfl_xor(sacc, 4);
      sacc += __shfl_xor(sacc, 8);
      if (l15 == 0) {
        const int m = rt * 128 + wr * 64 + i * 16 + lh * 4 + reg;
        atomicAdd(&scores[m], sacc);
      }
    }
  }
}

// ---------------- softmax over S per batch (in-place) ----------------
__global__ __launch_bounds__(256) void k_softmax(float* __restrict__ sc) {
  const int b = blockIdx.x, t = threadIdx.x;
  float4 x = *(float4*)(sc + b * NS + t * 4);
  float mx = fmaxf(fmaxf(x.x, x.y), fmaxf(x.z, x.w));
  #pragma unroll
  for (int m = 1; m < 64; m <<= 1) mx = fmaxf(mx, __shfl_xor(mx, m));
  __shared__ float rmax[4], rsum[4];
  if ((t & 63) == 0) rmax[t >> 6] = mx;
  __syncthreads();
  mx = fmaxf(fmaxf(rmax[0], rmax[1]), fmaxf(rmax[2], rmax[3]));
  float e0 = __expf(x.x - mx), e1 = __expf(x.y - mx);
  float e2 = __expf(x.z - mx), e3 = __expf(x.w - mx);
  float sm = e0 + e1 + e2 + e3;
  #pragma unroll
  for (int m = 1; m < 64; m <<= 1) sm += __shfl_xor(sm, m);
  if ((t & 63) == 0) rsum[t >> 6] = sm;
  __syncthreads();
  sm = rsum[0] + rsum[1] + rsum[2] + rsum[3];
  const float inv = 1.0f / sm;
  float4 o; o.x = e0 * inv; o.y = e1 * inv; o.z = e2 * inv; o.w = e3 * inv;
  *(float4*)(sc + b * NS + t * 4) = o;
}

// ---------------- context[b,e] = sum_s w[b,s] * enc[b,s,e] ----------------
template <int CONV>
__global__ __launch_bounds__(256) void k_ctx(const void* __restrict__ encsrc,
                                             const float* __restrict__ wgt,
                                             float* __restrict__ ctx) {
  const int b = blockIdx.x >> 4, scn = blockIdx.x & 15;   // 16 s-chunks of 64
  const int t = threadIdx.x;                              // 4 e's per thread
  float a0 = 0.f, a1 = 0.f, a2 = 0.f, a3 = 0.f;
  for (int s = scn * 64; s < scn * 64 + 64; ++s) {
    const float wv = wgt[b * NS + s];
    const size_t base = ((size_t)(b * NS + s)) * NE + t * 4;
    if constexpr (CONV) {
      float4 x = *((const float4*)((const float*)encsrc + base));
      a0 += wv * x.x; a1 += wv * x.y; a2 += wv * x.z; a3 += wv * x.w;
    } else {
      short4v hv = *(const short4v*)((const unsigned short*)encsrc + base);
      a0 += wv * bf2f((unsigned short)hv[0]);
      a1 += wv * bf2f((unsigned short)hv[1]);
      a2 += wv * bf2f((unsigned short)hv[2]);
      a3 += wv * bf2f((unsigned short)hv[3]);
    }
  }
  float* c = ctx + b * NE + t * 4;
  atomicAdd(c + 0, a0); atomicAdd(c + 1, a1);
  atomicAdd(c + 2, a2); atomicAdd(c + 3, a3);
}

// ---------------- ctx f32 -> f32 output (reference output dtype is float32) ----------------
__global__ __launch_bounds__(256) void k_out(const float* __restrict__ ctx,
                                             float* __restrict__ out) {
  const int i = blockIdx.x * 256 + threadIdx.x;   // 16384 threads x 4 floats
  float4 x = *(const float4*)(ctx + i * 4);
  *(float4*)(out + i * 4) = x;
}

extern "C" void kernel_launch(void* const* d_in, const int* in_sizes, int n_in,
                              void* d_out, int out_size, void* d_ws, size_t ws_size,
                              hipStream_t stream) {
  const float* hidden = (const float*)d_in[0];
  const float* enc    = (const float*)d_in[1];
  const float* W      = (const float*)d_in[2];
  const float* bias   = (const float*)d_in[3];
  const float* v      = (const float*)d_in[4];
  (void)in_sizes; (void)n_in; (void)out_size;

  char* ws = (char*)d_ws;
  const size_t T0 = (4ull << 20) + (128ull << 20);  // Wb + u/sc/ctx + enc_bf16
  const size_t T1 = (3ull << 20);                   // Wb + u/sc/ctx
  const int tier = (ws_size >= T0) ? 0 : ((ws_size >= T1) ? 1 : 2);

  unsigned short* Wb   = (unsigned short*)ws;
  unsigned short* encb = (unsigned short*)(ws + (4ull << 20));
  float* u_  = (tier < 2) ? (float*)(ws + (2ull << 20)) : (float*)ws;
  float* sc  = u_ + NB * NA;
  float* ctx = sc + NB * NS;

  k_u<<<512, 256, 0, stream>>>(hidden, W, bias, u_);
  k_zero<<<128, 256, 0, stream>>>((float4*)sc, (NB * NS + NB * NE) / 4);

  if (tier == 0) {
    k_conv_w<<<512, 256, 0, stream>>>(W, (short8*)Wb);
    k_main256f<<<1024, 512, 0, stream>>>(enc, Wb, u_, v, sc, encb);
  } else if (tier == 1) {
    k_conv_w<<<512, 256, 0, stream>>>(W, (short8*)Wb);
    k_main_rs<1, 0><<<4096, 256, 0, stream>>>(enc, Wb, u_, v, sc);
  } else {
    k_main_rs<1, 1><<<4096, 256, 0, stream>>>(enc, W, u_, v, sc);
  }

  k_softmax<<<64, 256, 0, stream>>>(sc);
  if (tier == 0) k_ctx<0><<<1024, 256, 0, stream>>>(encb, sc, ctx);
  else           k_ctx<1><<<1024, 256, 0, stream>>>(enc, sc, ctx);
  k_out<<<64, 256, 0, stream>>>(ctx, (float*)d_out);
}

// Round 15
// 281.435 us; speedup vs baseline: 1.4092x; 1.4092x over previous
//
#include <hip/hip_runtime.h>
#include <hip/hip_bf16.h>
#include <stdint.h>

// Problem constants (Attention_21552145891894): B=64, S=1024, DEC=ENC=ATTN=1024
#define NB 64
#define NS 1024
#define NE 1024   // ENC (= K of big GEMM)
#define NA 1024   // ATTN (= N of big GEMM)
#define NF 2048   // DEC+ENC (W_attn row length)
#define LDP 144   // padded LDS row stride (fallback reg-staged kernel only)

typedef __attribute__((ext_vector_type(8))) short   short8;
typedef __attribute__((ext_vector_type(4))) short   short4v;
typedef __attribute__((ext_vector_type(4))) float   f32x4;
typedef __attribute__((ext_vector_type(8))) __bf16  bf16x8;

__device__ __forceinline__ unsigned short f2bf(float x) {
  union { float f; unsigned u; } v; v.f = x;
  unsigned r = v.u + 0x7fffu + ((v.u >> 16) & 1u);   // RNE
  return (unsigned short)(r >> 16);
}
__device__ __forceinline__ float bf2f(unsigned short h) {
  union { unsigned u; float f; } v; v.u = ((unsigned)h) << 16;
  return v.f;
}
__device__ __forceinline__ float tanh_fast(float x) {
  float e = __expf(2.0f * x);                        // overflow -> inf -> 1; underflow -> -1
  return 1.0f - __fdividef(2.0f, e + 1.0f);
}
__device__ __forceinline__ short8 pack8(float4 a, float4 b) {
  short8 h;
  h[0]=(short)f2bf(a.x); h[1]=(short)f2bf(a.y); h[2]=(short)f2bf(a.z); h[3]=(short)f2bf(a.w);
  h[4]=(short)f2bf(b.x); h[5]=(short)f2bf(b.y); h[6]=(short)f2bf(b.z); h[7]=(short)f2bf(b.w);
  return h;
}
__device__ __forceinline__ void gload_lds16(const void* g, void* l) {
  // HW: LDS dest is wave-uniform base + lane*16; size must be literal 16 (m97/m104)
  __builtin_amdgcn_global_load_lds((const __attribute__((address_space(1))) void*)g,
                                   (__attribute__((address_space(3))) void*)l, 16, 0, 0);
}

// ---------------- zero scratch (scores + ctx), deterministic each call ----------------
__global__ __launch_bounds__(256) void k_zero(float4* __restrict__ p, int n4) {
  int i = blockIdx.x * 256 + threadIdx.x;
  if (i < n4) { float4 z; z.x = z.y = z.z = z.w = 0.f; p[i] = z; }
}

// ---------------- enc f32 -> bf16 (ws) ----------------
__global__ __launch_bounds__(256) void k_conv_enc(const float4* __restrict__ src,
                                                  short8* __restrict__ dst, int n8) {
  int i = blockIdx.x * 256 + threadIdx.x;
  const int stride = gridDim.x * 256;
  for (; i < n8; i += stride) {
    float4 a = src[2 * i], b = src[2 * i + 1];
    dst[i] = pack8(a, b);
  }
}

// ---------------- W_enc (= W_attn[:,1024:2048]) f32 -> bf16 [1024][1024] ----------------
__global__ __launch_bounds__(256) void k_conv_w(const float* __restrict__ W, short8* __restrict__ dst) {
  const int id = blockIdx.x * 256 + threadIdx.x;   // 131072 total
  const int a = id >> 7, ku = id & 127;
  const float* s = W + (size_t)a * NF + 1024 + ku * 8;
  float4 x = *(const float4*)s;
  float4 y = *(const float4*)(s + 4);
  dst[id] = pack8(x, y);
}

// ---------------- u[b,a] = hidden[b] . W_attn[a,0:1024] + b_attn[a]  (fp32 exact) ----------------
__global__ __launch_bounds__(256) void k_u(const float* __restrict__ hidden,
                                           const float* __restrict__ W,
                                           const float* __restrict__ bias,
                                           float* __restrict__ u) {
  const int l = threadIdx.x & 63;
  const int w = threadIdx.x >> 6;
  const int a = (blockIdx.x >> 1) * 4 + w;         // grid 512 -> a in [0,1024)
  const int bh = blockIdx.x & 1;
  const float* wrow = W + (size_t)a * NF;          // dec half: cols 0..1023
  float4 wv[4];
  #pragma unroll
  for (int i = 0; i < 4; ++i) wv[i] = *(const float4*)(wrow + l * 4 + i * 256);
  const float ba = bias[a];
  for (int b = bh * 32; b < bh * 32 + 32; ++b) {
    const float* hrow = hidden + b * 1024;
    float s = 0.f;
    #pragma unroll
    for (int i = 0; i < 4; ++i) {
      float4 hv = *(const float4*)(hrow + l * 4 + i * 256);
      s += wv[i].x * hv.x + wv[i].y * hv.y + wv[i].z * hv.z + wv[i].w * hv.w;
    }
    #pragma unroll
    for (int m = 1; m < 64; m <<= 1) s += __shfl_xor(s, m);
    if (l == 0) u[b * NA + a] = s + ba;
  }
}

// ======== main fused GEMM (tier0): 256x256 tile, double-buffered, 1 barrier/K-tile ========
// Round-7 verified optimum (193us, 712 TF, MfmaUtil 30%) — best of 7 structural
// variants (drain-0 mono, 4-phase, counted-vmcnt, m201-discipline, B-direct x2,
// fused-conv). 8 waves (2M x 4N), wave tile 128x64. LDS: 2 x 64KB buffers. Per
// K-tile: vmcnt(0) (loads aged a full tile) + raw barrier, stage t+1 into the
// opposite buffer, hoisted A-frags, 2 x {B-frags + setprio + 32 MFMA}.
// k-unit XOR swizzle both-sides (r5-verified, 0 bank conflicts).
__global__ __launch_bounds__(512, 2) void k_main256(const unsigned short* __restrict__ Ab,
                                                    const unsigned short* __restrict__ Bb,
                                                    const float* __restrict__ u_,
                                                    const float* __restrict__ v_,
                                                    float* __restrict__ scores) {
  __shared__ __align__(16) char smem[2 * 65536];

  const int tid = threadIdx.x;
  const int l = tid & 63;
  const int w = tid >> 6;                   // 0..7
  const int wr = w >> 2, wc = w & 3;        // 2M x 4N wave grid
  // XCD-chunked remap (bijective: 1024 = 8 xcd * 128): one rt's 4 col-tiles are
  // consecutive dispatches on one XCD -> A-panel L2 reuse; Wb (2MB) L2-resident.
  const int d = blockIdx.x;
  const int xcd = d & 7, q = d >> 3;
  const int rt = xcd * 32 + (q >> 2);       // row tile [0,256)
  const int ct = q & 3;                     // col tile [0,4)
  const int b = rt >> 2;                    // batch (256-row tiles never straddle)
  const int lh = l >> 4, l15 = l & 15, l7 = l & 7;

  // staging: 512 threads x 16B = 64 rows/issue; lane -> row (tid>>3), k-unit (tid&7);
  // source pre-swizzled by row&7 (rule #21 involution, r5-verified)
  const int ssk = ((tid & 7) ^ ((tid >> 3) & 7)) * 8;
  const unsigned short* aS = Ab + (size_t)(rt * 256 + (tid >> 3)) * NE + ssk;
  const unsigned short* bS = Bb + (size_t)(ct * 256 + (tid >> 3)) * NE + ssk;
  const int wdst = w * 1024;                // wave-uniform LDS dest offset

  f32x4 acc[8][4] = {};

#define STAGE256(tt) do { \
    char* dst_ = smem + (((tt) & 1) << 16); \
    const unsigned short* a_ = aS + (size_t)(tt) * 64; \
    const unsigned short* b_ = bS + (size_t)(tt) * 64; \
    gload_lds16(a_,                    dst_ + wdst); \
    gload_lds16(a_ + (size_t) 64 * NE, dst_ +  64 * 128 + wdst); \
    gload_lds16(a_ + (size_t)128 * NE, dst_ + 128 * 128 + wdst); \
    gload_lds16(a_ + (size_t)192 * NE, dst_ + 192 * 128 + wdst); \
    gload_lds16(b_,                    dst_ + 32768 + wdst); \
    gload_lds16(b_ + (size_t) 64 * NE, dst_ + 32768 +  64 * 128 + wdst); \
    gload_lds16(b_ + (size_t)128 * NE, dst_ + 32768 + 128 * 128 + wdst); \
    gload_lds16(b_ + (size_t)192 * NE, dst_ + 32768 + 192 * 128 + wdst); } while (0)

  STAGE256(0);                              // prologue: tile 0 into buf 0

  for (int t = 0; t < 16; ++t) {
    asm volatile("s_waitcnt vmcnt(0)" ::: "memory");   // tile t certified (aged 1 tile)
    asm volatile("s_barrier" ::: "memory");            // buf (t+1)&1 free of readers
    if (t < 15) STAGE256(t + 1);                       // overlaps with compute below

    const char* As = smem + ((t & 1) << 16);
    const char* Bs = As + 32768;

    bf16x8 areg[8][2];
    #pragma unroll
    for (int rf = 0; rf < 8; ++rf)
      #pragma unroll
      for (int kh = 0; kh < 2; ++kh)
        areg[rf][kh] = *(const bf16x8*)(As + (wr * 128 + rf * 16 + l15) * 128
                                           + (((kh * 4 + lh) ^ l7) << 4));
    #pragma unroll
    for (int cfh = 0; cfh < 2; ++cfh) {
      bf16x8 breg[2][2];
      #pragma unroll
      for (int c2 = 0; c2 < 2; ++c2)
        #pragma unroll
        for (int kh = 0; kh < 2; ++kh)
          breg[c2][kh] = *(const bf16x8*)(Bs + (wc * 64 + (cfh * 2 + c2) * 16 + l15) * 128
                                             + (((kh * 4 + lh) ^ l7) << 4));
      __builtin_amdgcn_s_setprio(1);
      #pragma unroll
      for (int rf = 0; rf < 8; ++rf)
        #pragma unroll
        for (int c2 = 0; c2 < 2; ++c2)
          #pragma unroll
          for (int kh = 0; kh < 2; ++kh)
            acc[rf][cfh * 2 + c2] = __builtin_amdgcn_mfma_f32_16x16x32_bf16(
                areg[rf][kh], breg[c2][kh], acc[rf][cfh * 2 + c2], 0, 0, 0);
      __builtin_amdgcn_s_setprio(0);
    }
  }
#undef STAGE256

  // ---- epilogue: D frag col=l&15, row=(l>>4)*4+reg (m89-verified) ----
  const int colb = ct * 256 + wc * 64 + l15;
  float uv[4], vv[4];
  #pragma unroll
  for (int cf = 0; cf < 4; ++cf) {
    const int c = colb + cf * 16;
    uv[cf] = u_[b * NA + c];
    vv[cf] = v_[c];
  }
  #pragma unroll
  for (int rf = 0; rf < 8; ++rf) {
    #pragma unroll
    for (int reg = 0; reg < 4; ++reg) {
      float sacc = 0.f;
      #pragma unroll
      for (int cf = 0; cf < 4; ++cf)
        sacc += tanh_fast(acc[rf][cf][reg] + uv[cf]) * vv[cf];
      sacc += __shfl_xor(sacc, 1);
      sacc += __shfl_xor(sacc, 2);
      sacc += __shfl_xor(sacc, 4);
      sacc += __shfl_xor(sacc, 8);
      if (l15 == 0) {
        const int m = rt * 256 + wr * 128 + rf * 16 + lh * 4 + reg;
        atomicAdd(&scores[m], sacc);         // 16 partials per row (4 ct x 4 wc)
      }
    }
  }
}

// ======== fallback (small ws): reg-staged padded-LDS version (round-3-verified) ========
template <int ACONV, int BCONV>
__global__ __launch_bounds__(256) void k_main_rs(const void* __restrict__ Asrc,
                                                 const void* __restrict__ Bsrc,
                                                 const float* __restrict__ u_,
                                                 const float* __restrict__ v_,
                                                 float* __restrict__ scores) {
  __shared__ __align__(16) char smemf[2 * 128 * LDP];
  char* As = smemf;
  char* Bs = smemf + 128 * LDP;
  const int tid = threadIdx.x;
  const int l = tid & 63;
  const int w = tid >> 6;
  const int wr = w >> 1, wc = w & 1;
  const int d = blockIdx.x;
  const int rt = (d & 7) * 64 + (d >> 6);
  const int ct = (d >> 3) & 7;
  const int b = rt >> 3;
  const int l7 = l & 7, lh = l >> 4, l15 = l & 15;
  const int srow = w * 8 + (l >> 3);
  f32x4 acc[4][4] = {};
  for (int kt = 0; kt < 16; ++kt) {
    const int k0 = kt * 64;
    __syncthreads();
    #pragma unroll
    for (int r = 0; r < 4; ++r) {
      const int row = r * 32 + srow;
      short8 val;
      if constexpr (ACONV) {
        const float* s = (const float*)Asrc + (size_t)(rt * 128 + row) * NE + k0 + l7 * 8;
        val = pack8(*(const float4*)s, *(const float4*)(s + 4));
      } else {
        val = *(const short8*)((const unsigned short*)Asrc + (size_t)(rt * 128 + row) * NE + k0 + l7 * 8);
      }
      *(short8*)(As + row * LDP + l7 * 16) = val;
    }
    #pragma unroll
    for (int r = 0; r < 4; ++r) {
      const int row = r * 32 + srow;
      short8 val;
      if constexpr (BCONV) {
        const float* s = (const float*)Bsrc + (size_t)(ct * 128 + row) * NF + 1024 + k0 + l7 * 8;
        val = pack8(*(const float4*)s, *(const float4*)(s + 4));
      } else {
        val = *(const short8*)((const unsigned short*)Bsrc + (size_t)(ct * 128 + row) * NE + k0 + l7 * 8);
      }
      *(short8*)(Bs + row * LDP + l7 * 16) = val;
    }
    __syncthreads();
    #pragma unroll
    for (int ks = 0; ks < 2; ++ks) {
      bf16x8 af[4], bfr[4];
      const int ku = (ks * 4 + lh) * 16;
      #pragma unroll
      for (int f = 0; f < 4; ++f) {
        af[f]  = *(const bf16x8*)(As + (wr * 64 + f * 16 + l15) * LDP + ku);
        bfr[f] = *(const bf16x8*)(Bs + (wc * 64 + f * 16 + l15) * LDP + ku);
      }
      #pragma unroll
      for (int i = 0; i < 4; ++i)
        #pragma unroll
        for (int jj = 0; jj < 4; ++jj)
          acc[i][jj] = __builtin_amdgcn_mfma_f32_16x16x32_bf16(af[i], bfr[jj], acc[i][jj], 0, 0, 0);
    }
  }
  const int colb = ct * 128 + wc * 64 + l15;
  float uv[4], vv[4];
  #pragma unroll
  for (int jj = 0; jj < 4; ++jj) {
    const int c = colb + jj * 16;
    uv[jj] = u_[b * NA + c];
    vv[jj] = v_[c];
  }
  #pragma unroll
  for (int i = 0; i < 4; ++i) {
    #pragma unroll
    for (int reg = 0; reg < 4; ++reg) {
      float sacc = 0.f;
      #pragma unroll
      for (int jj = 0; jj < 4; ++jj)
        sacc += tanh_fast(acc[i][jj][reg] + uv[jj]) * vv[jj];
      sacc += __shfl_xor(sacc, 1);
      sacc += __shfl_xor(sacc, 2);
      sacc += __shfl_xor(sacc, 4);
      sacc += __shfl_xor(sacc, 8);
      if (l15 == 0) {
        const int m = rt * 128 + wr * 64 + i * 16 + lh * 4 + reg;
        atomicAdd(&scores[m], sacc);
      }
    }
  }
}

// ---------------- softmax over S per batch (in-place) ----------------
__global__ __launch_bounds__(256) void k_softmax(float* __restrict__ sc) {
  const int b = blockIdx.x, t = threadIdx.x;
  float4 x = *(float4*)(sc + b * NS + t * 4);
  float mx = fmaxf(fmaxf(x.x, x.y), fmaxf(x.z, x.w));
  #pragma unroll
  for (int m = 1; m < 64; m <<= 1) mx = fmaxf(mx, __shfl_xor(mx, m));
  __shared__ float rmax[4], rsum[4];
  if ((t & 63) == 0) rmax[t >> 6] = mx;
  __syncthreads();
  mx = fmaxf(fmaxf(rmax[0], rmax[1]), fmaxf(rmax[2], rmax[3]));
  float e0 = __expf(x.x - mx), e1 = __expf(x.y - mx);
  float e2 = __expf(x.z - mx), e3 = __expf(x.w - mx);
  float sm = e0 + e1 + e2 + e3;
  #pragma unroll
  for (int m = 1; m < 64; m <<= 1) sm += __shfl_xor(sm, m);
  if ((t & 63) == 0) rsum[t >> 6] = sm;
  __syncthreads();
  sm = rsum[0] + rsum[1] + rsum[2] + rsum[3];
  const float inv = 1.0f / sm;
  float4 o; o.x = e0 * inv; o.y = e1 * inv; o.z = e2 * inv; o.w = e3 * inv;
  *(float4*)(sc + b * NS + t * 4) = o;
}

// ---------------- context[b,e] = sum_s w[b,s] * enc[b,s,e] ----------------
template <int CONV>
__global__ __launch_bounds__(256) void k_ctx(const void* __restrict__ encsrc,
                                             const float* __restrict__ wgt,
                                             float* __restrict__ ctx) {
  const int b = blockIdx.x >> 4, scn = blockIdx.x & 15;   // 16 s-chunks of 64
  const int t = threadIdx.x;                              // 4 e's per thread
  float a0 = 0.f, a1 = 0.f, a2 = 0.f, a3 = 0.f;
  for (int s = scn * 64; s < scn * 64 + 64; ++s) {
    const float wv = wgt[b * NS + s];
    const size_t base = ((size_t)(b * NS + s)) * NE + t * 4;
    if constexpr (CONV) {
      float4 x = *((const float4*)((const float*)encsrc + base));
      a0 += wv * x.x; a1 += wv * x.y; a2 += wv * x.z; a3 += wv * x.w;
    } else {
      short4v hv = *(const short4v*)((const unsigned short*)encsrc + base);
      a0 += wv * bf2f((unsigned short)hv[0]);
      a1 += wv * bf2f((unsigned short)hv[1]);
      a2 += wv * bf2f((unsigned short)hv[2]);
      a3 += wv * bf2f((unsigned short)hv[3]);
    }
  }
  float* c = ctx + b * NE + t * 4;
  atomicAdd(c + 0, a0); atomicAdd(c + 1, a1);
  atomicAdd(c + 2, a2); atomicAdd(c + 3, a3);
}

// ---------------- ctx f32 -> f32 output (reference output dtype is float32) ----------------
__global__ __launch_bounds__(256) void k_out(const float* __restrict__ ctx,
                                             float* __restrict__ out) {
  const int i = blockIdx.x * 256 + threadIdx.x;   // 16384 threads x 4 floats
  float4 x = *(const float4*)(ctx + i * 4);
  *(float4*)(out + i * 4) = x;
}

extern "C" void kernel_launch(void* const* d_in, const int* in_sizes, int n_in,
                              void* d_out, int out_size, void* d_ws, size_t ws_size,
                              hipStream_t stream) {
  const float* hidden = (const float*)d_in[0];
  const float* enc    = (const float*)d_in[1];
  const float* W      = (const float*)d_in[2];
  const float* bias   = (const float*)d_in[3];
  const float* v      = (const float*)d_in[4];
  (void)in_sizes; (void)n_in; (void)out_size;

  char* ws = (char*)d_ws;
  const size_t T0 = (4ull << 20) + (128ull << 20);  // Wb + u/sc/ctx + enc_bf16
  const size_t T1 = (3ull << 20);                   // Wb + u/sc/ctx
  const int tier = (ws_size >= T0) ? 0 : ((ws_size >= T1) ? 1 : 2);

  unsigned short* Wb   = (unsigned short*)ws;
  unsigned short* encb = (unsigned short*)(ws + (4ull << 20));
  float* u_  = (tier < 2) ? (float*)(ws + (2ull << 20)) : (float*)ws;
  float* sc  = u_ + NB * NA;
  float* ctx = sc + NB * NS;

  k_u<<<512, 256, 0, stream>>>(hidden, W, bias, u_);
  k_zero<<<128, 256, 0, stream>>>((float4*)sc, (NB * NS + NB * NE) / 4);

  if (tier == 0) {
    k_conv_w<<<512, 256, 0, stream>>>(W, (short8*)Wb);
    k_conv_enc<<<2048, 256, 0, stream>>>((const float4*)enc, (short8*)encb, NB * NS * NE / 8);
    k_main256<<<1024, 512, 0, stream>>>(encb, Wb, u_, v, sc);
  } else if (tier == 1) {
    k_conv_w<<<512, 256, 0, stream>>>(W, (short8*)Wb);
    k_main_rs<1, 0><<<4096, 256, 0, stream>>>(enc, Wb, u_, v, sc);
  } else {
    k_main_rs<1, 1><<<4096, 256, 0, stream>>>(enc, W, u_, v, sc);
  }

  k_softmax<<<64, 256, 0, stream>>>(sc);
  if (tier == 0) k_ctx<0><<<1024, 256, 0, stream>>>(encb, sc, ctx);
  else           k_ctx<1><<<1024, 256, 0, stream>>>(enc, sc, ctx);
  k_out<<<64, 256, 0, stream>>>(ctx, (float*)d_out);
}

// Round 16
// 253.343 us; speedup vs baseline: 1.5654x; 1.1109x over previous
//
#include <hip/hip_runtime.h>
#include <hip/hip_bf16.h>
#include <stdint.h>

// Problem constants (Attention_21552145891894): B=64, S=1024, DEC=ENC=ATTN=1024
#define NB 64
#define NS 1024
#define NE 1024   // ENC (= K of big GEMM)
#define NA 1024   // ATTN (= N of big GEMM)
#define NF 2048   // DEC+ENC (W_attn row length)
#define LDP 144   // padded LDS row stride (fallback reg-staged kernel only)

typedef __attribute__((ext_vector_type(8))) short   short8;
typedef __attribute__((ext_vector_type(4))) short   short4v;
typedef __attribute__((ext_vector_type(4))) float   f32x4;
typedef __attribute__((ext_vector_type(8))) __bf16  bf16x8;

__device__ __forceinline__ unsigned short f2bf(float x) {
  union { float f; unsigned u; } v; v.f = x;
  unsigned r = v.u + 0x7fffu + ((v.u >> 16) & 1u);   // RNE
  return (unsigned short)(r >> 16);
}
__device__ __forceinline__ float bf2f(unsigned short h) {
  union { unsigned u; float f; } v; v.u = ((unsigned)h) << 16;
  return v.f;
}
__device__ __forceinline__ float tanh_fast(float x) {
  float e = __expf(2.0f * x);                        // overflow -> inf -> 1; underflow -> -1
  return 1.0f - __fdividef(2.0f, e + 1.0f);
}
__device__ __forceinline__ short8 pack8(float4 a, float4 b) {
  short8 h;
  h[0]=(short)f2bf(a.x); h[1]=(short)f2bf(a.y); h[2]=(short)f2bf(a.z); h[3]=(short)f2bf(a.w);
  h[4]=(short)f2bf(b.x); h[5]=(short)f2bf(b.y); h[6]=(short)f2bf(b.z); h[7]=(short)f2bf(b.w);
  return h;
}
__device__ __forceinline__ void gload_lds16(const void* g, void* l) {
  // HW: LDS dest is wave-uniform base + lane*16; size must be literal 16 (m97/m104)
  __builtin_amdgcn_global_load_lds((const __attribute__((address_space(1))) void*)g,
                                   (__attribute__((address_space(3))) void*)l, 16, 0, 0);
}

// ======== fused pre-pass (tier0): k_u | k_zero | conv_w | conv_enc in one dispatch ========
// All four sub-kernels are mutually independent (write u_/sc+ctx/Wb/encb); block-range
// dispatch, per-block uniform branch (no divergence). Saves 3 dispatch gaps.
__global__ __launch_bounds__(256) void k_pre(const float* __restrict__ hidden,
                                             const float* __restrict__ W,
                                             const float* __restrict__ bias,
                                             float* __restrict__ u_,
                                             float4* __restrict__ zbase,
                                             short8* __restrict__ Wb,
                                             const float4* __restrict__ encf,
                                             short8* __restrict__ encb) {
  const int bid = blockIdx.x;
  const int tid = threadIdx.x;
  if (bid < 512) {
    // ---- k_u: u[b,a] = hidden[b] . W[a,0:1024] + bias[a] (fp32 exact) ----
    const int l = tid & 63;
    const int w = tid >> 6;
    const int a = (bid >> 1) * 4 + w;
    const int bh = bid & 1;
    const float* wrow = W + (size_t)a * NF;
    float4 wv[4];
    #pragma unroll
    for (int i = 0; i < 4; ++i) wv[i] = *(const float4*)(wrow + l * 4 + i * 256);
    const float ba = bias[a];
    for (int b = bh * 32; b < bh * 32 + 32; ++b) {
      const float* hrow = hidden + b * 1024;
      float s = 0.f;
      #pragma unroll
      for (int i = 0; i < 4; ++i) {
        float4 hv = *(const float4*)(hrow + l * 4 + i * 256);
        s += wv[i].x * hv.x + wv[i].y * hv.y + wv[i].z * hv.z + wv[i].w * hv.w;
      }
      #pragma unroll
      for (int m = 1; m < 64; m <<= 1) s += __shfl_xor(s, m);
      if (l == 0) u_[b * NA + a] = s + ba;
    }
  } else if (bid < 640) {
    // ---- k_zero: sc (64x1024) + ctx (64x1024) f32 -> 32768 float4 ----
    const int i = (bid - 512) * 256 + tid;
    float4 z; z.x = z.y = z.z = z.w = 0.f;
    zbase[i] = z;
  } else if (bid < 1152) {
    // ---- conv_w: W_enc f32 -> bf16 [1024][1024] ----
    const int id = (bid - 640) * 256 + tid;
    const int a = id >> 7, ku = id & 127;
    const float* s = W + (size_t)a * NF + 1024 + ku * 8;
    Wb[id] = pack8(*(const float4*)s, *(const float4*)(s + 4));
  } else {
    // ---- conv_enc: enc f32 -> bf16 (grid-stride, 2048 blocks) ----
    const int n8 = NB * NS * NE / 8;
    int i = (bid - 1152) * 256 + tid;
    const int stride = 2048 * 256;
    for (; i < n8; i += stride) {
      float4 a = encf[2 * i], b = encf[2 * i + 1];
      encb[i] = pack8(a, b);
    }
  }
}

// ---------------- standalone versions (tier1/2 fallback paths) ----------------
__global__ __launch_bounds__(256) void k_zero(float4* __restrict__ p, int n4) {
  int i = blockIdx.x * 256 + threadIdx.x;
  if (i < n4) { float4 z; z.x = z.y = z.z = z.w = 0.f; p[i] = z; }
}
__global__ __launch_bounds__(256) void k_conv_w(const float* __restrict__ W, short8* __restrict__ dst) {
  const int id = blockIdx.x * 256 + threadIdx.x;
  const int a = id >> 7, ku = id & 127;
  const float* s = W + (size_t)a * NF + 1024 + ku * 8;
  dst[id] = pack8(*(const float4*)s, *(const float4*)(s + 4));
}
__global__ __launch_bounds__(256) void k_u(const float* __restrict__ hidden,
                                           const float* __restrict__ W,
                                           const float* __restrict__ bias,
                                           float* __restrict__ u) {
  const int l = threadIdx.x & 63;
  const int w = threadIdx.x >> 6;
  const int a = (blockIdx.x >> 1) * 4 + w;
  const int bh = blockIdx.x & 1;
  const float* wrow = W + (size_t)a * NF;
  float4 wv[4];
  #pragma unroll
  for (int i = 0; i < 4; ++i) wv[i] = *(const float4*)(wrow + l * 4 + i * 256);
  const float ba = bias[a];
  for (int b = bh * 32; b < bh * 32 + 32; ++b) {
    const float* hrow = hidden + b * 1024;
    float s = 0.f;
    #pragma unroll
    for (int i = 0; i < 4; ++i) {
      float4 hv = *(const float4*)(hrow + l * 4 + i * 256);
      s += wv[i].x * hv.x + wv[i].y * hv.y + wv[i].z * hv.z + wv[i].w * hv.w;
    }
    #pragma unroll
    for (int m = 1; m < 64; m <<= 1) s += __shfl_xor(s, m);
    if (l == 0) u[b * NA + a] = s + ba;
  }
}

// ======== main fused GEMM (tier0): 256x256 tile, double-buffered, 1 barrier/K-tile ========
// Round-7/15 verified optimum (193us, 712 TF, MfmaUtil 30%) — best of 7 structural
// variants; at the reproducible-structure ceiling (m230 2ph ref = 682 TF). UNCHANGED.
__global__ __launch_bounds__(512, 2) void k_main256(const unsigned short* __restrict__ Ab,
                                                    const unsigned short* __restrict__ Bb,
                                                    const float* __restrict__ u_,
                                                    const float* __restrict__ v_,
                                                    float* __restrict__ scores) {
  __shared__ __align__(16) char smem[2 * 65536];

  const int tid = threadIdx.x;
  const int l = tid & 63;
  const int w = tid >> 6;                   // 0..7
  const int wr = w >> 2, wc = w & 3;        // 2M x 4N wave grid
  const int d = blockIdx.x;
  const int xcd = d & 7, q = d >> 3;
  const int rt = xcd * 32 + (q >> 2);       // row tile [0,256)
  const int ct = q & 3;                     // col tile [0,4)
  const int b = rt >> 2;                    // batch (256-row tiles never straddle)
  const int lh = l >> 4, l15 = l & 15, l7 = l & 7;

  const int ssk = ((tid & 7) ^ ((tid >> 3) & 7)) * 8;
  const unsigned short* aS = Ab + (size_t)(rt * 256 + (tid >> 3)) * NE + ssk;
  const unsigned short* bS = Bb + (size_t)(ct * 256 + (tid >> 3)) * NE + ssk;
  const int wdst = w * 1024;                // wave-uniform LDS dest offset

  f32x4 acc[8][4] = {};

#define STAGE256(tt) do { \
    char* dst_ = smem + (((tt) & 1) << 16); \
    const unsigned short* a_ = aS + (size_t)(tt) * 64; \
    const unsigned short* b_ = bS + (size_t)(tt) * 64; \
    gload_lds16(a_,                    dst_ + wdst); \
    gload_lds16(a_ + (size_t) 64 * NE, dst_ +  64 * 128 + wdst); \
    gload_lds16(a_ + (size_t)128 * NE, dst_ + 128 * 128 + wdst); \
    gload_lds16(a_ + (size_t)192 * NE, dst_ + 192 * 128 + wdst); \
    gload_lds16(b_,                    dst_ + 32768 + wdst); \
    gload_lds16(b_ + (size_t) 64 * NE, dst_ + 32768 +  64 * 128 + wdst); \
    gload_lds16(b_ + (size_t)128 * NE, dst_ + 32768 + 128 * 128 + wdst); \
    gload_lds16(b_ + (size_t)192 * NE, dst_ + 32768 + 192 * 128 + wdst); } while (0)

  STAGE256(0);                              // prologue: tile 0 into buf 0

  for (int t = 0; t < 16; ++t) {
    asm volatile("s_waitcnt vmcnt(0)" ::: "memory");   // tile t certified (aged 1 tile)
    asm volatile("s_barrier" ::: "memory");            // buf (t+1)&1 free of readers
    if (t < 15) STAGE256(t + 1);                       // overlaps with compute below

    const char* As = smem + ((t & 1) << 16);
    const char* Bs = As + 32768;

    bf16x8 areg[8][2];
    #pragma unroll
    for (int rf = 0; rf < 8; ++rf)
      #pragma unroll
      for (int kh = 0; kh < 2; ++kh)
        areg[rf][kh] = *(const bf16x8*)(As + (wr * 128 + rf * 16 + l15) * 128
                                           + (((kh * 4 + lh) ^ l7) << 4));
    #pragma unroll
    for (int cfh = 0; cfh < 2; ++cfh) {
      bf16x8 breg[2][2];
      #pragma unroll
      for (int c2 = 0; c2 < 2; ++c2)
        #pragma unroll
        for (int kh = 0; kh < 2; ++kh)
          breg[c2][kh] = *(const bf16x8*)(Bs + (wc * 64 + (cfh * 2 + c2) * 16 + l15) * 128
                                             + (((kh * 4 + lh) ^ l7) << 4));
      __builtin_amdgcn_s_setprio(1);
      #pragma unroll
      for (int rf = 0; rf < 8; ++rf)
        #pragma unroll
        for (int c2 = 0; c2 < 2; ++c2)
          #pragma unroll
          for (int kh = 0; kh < 2; ++kh)
            acc[rf][cfh * 2 + c2] = __builtin_amdgcn_mfma_f32_16x16x32_bf16(
                areg[rf][kh], breg[c2][kh], acc[rf][cfh * 2 + c2], 0, 0, 0);
      __builtin_amdgcn_s_setprio(0);
    }
  }
#undef STAGE256

  // ---- epilogue: D frag col=l&15, row=(l>>4)*4+reg (m89-verified) ----
  const int colb = ct * 256 + wc * 64 + l15;
  float uv[4], vv[4];
  #pragma unroll
  for (int cf = 0; cf < 4; ++cf) {
    const int c = colb + cf * 16;
    uv[cf] = u_[b * NA + c];
    vv[cf] = v_[c];
  }
  #pragma unroll
  for (int rf = 0; rf < 8; ++rf) {
    #pragma unroll
    for (int reg = 0; reg < 4; ++reg) {
      float sacc = 0.f;
      #pragma unroll
      for (int cf = 0; cf < 4; ++cf)
        sacc += tanh_fast(acc[rf][cf][reg] + uv[cf]) * vv[cf];
      sacc += __shfl_xor(sacc, 1);
      sacc += __shfl_xor(sacc, 2);
      sacc += __shfl_xor(sacc, 4);
      sacc += __shfl_xor(sacc, 8);
      if (l15 == 0) {
        const int m = rt * 256 + wr * 128 + rf * 16 + lh * 4 + reg;
        atomicAdd(&scores[m], sacc);         // 16 partials per row (4 ct x 4 wc)
      }
    }
  }
}

// ======== fused softmax+context (tier0): per (b, s-chunk) block ========
// Each of the 16 blocks per batch recomputes the row softmax (4KB read, reduction
// replicated op-for-op from k_softmax -> bit-identical weights), stores w in LDS,
// then runs its k_ctx chunk. Saves the softmax dispatch + sc round trip.
__global__ __launch_bounds__(256) void k_smctx(const float* __restrict__ sc,
                                               const unsigned short* __restrict__ encb,
                                               float* __restrict__ ctx) {
  const int b = blockIdx.x >> 4, scn = blockIdx.x & 15;
  const int t = threadIdx.x;
  __shared__ float rmax[4], rsum[4];
  __shared__ float wbuf[NS];

  float4 x = *(const float4*)(sc + b * NS + t * 4);
  float mx = fmaxf(fmaxf(x.x, x.y), fmaxf(x.z, x.w));
  #pragma unroll
  for (int m = 1; m < 64; m <<= 1) mx = fmaxf(mx, __shfl_xor(mx, m));
  if ((t & 63) == 0) rmax[t >> 6] = mx;
  __syncthreads();
  mx = fmaxf(fmaxf(rmax[0], rmax[1]), fmaxf(rmax[2], rmax[3]));
  float e0 = __expf(x.x - mx), e1 = __expf(x.y - mx);
  float e2 = __expf(x.z - mx), e3 = __expf(x.w - mx);
  float sm = e0 + e1 + e2 + e3;
  #pragma unroll
  for (int m = 1; m < 64; m <<= 1) sm += __shfl_xor(sm, m);
  if ((t & 63) == 0) rsum[t >> 6] = sm;
  __syncthreads();
  sm = rsum[0] + rsum[1] + rsum[2] + rsum[3];
  const float inv = 1.0f / sm;
  wbuf[t * 4 + 0] = e0 * inv;
  wbuf[t * 4 + 1] = e1 * inv;
  wbuf[t * 4 + 2] = e2 * inv;
  wbuf[t * 4 + 3] = e3 * inv;
  __syncthreads();

  float a0 = 0.f, a1 = 0.f, a2 = 0.f, a3 = 0.f;
  for (int s = scn * 64; s < scn * 64 + 64; ++s) {
    const float wv = wbuf[s];
    const size_t base = ((size_t)(b * NS + s)) * NE + t * 4;
    short4v hv = *(const short4v*)(encb + base);
    a0 += wv * bf2f((unsigned short)hv[0]);
    a1 += wv * bf2f((unsigned short)hv[1]);
    a2 += wv * bf2f((unsigned short)hv[2]);
    a3 += wv * bf2f((unsigned short)hv[3]);
  }
  float* c = ctx + b * NE + t * 4;
  atomicAdd(c + 0, a0); atomicAdd(c + 1, a1);
  atomicAdd(c + 2, a2); atomicAdd(c + 3, a3);
}

// ======== fallback (small ws): reg-staged padded-LDS version (round-3-verified) ========
template <int ACONV, int BCONV>
__global__ __launch_bounds__(256) void k_main_rs(const void* __restrict__ Asrc,
                                                 const void* __restrict__ Bsrc,
                                                 const float* __restrict__ u_,
                                                 const float* __restrict__ v_,
                                                 float* __restrict__ scores) {
  __shared__ __align__(16) char smemf[2 * 128 * LDP];
  char* As = smemf;
  char* Bs = smemf + 128 * LDP;
  const int tid = threadIdx.x;
  const int l = tid & 63;
  const int w = tid >> 6;
  const int wr = w >> 1, wc = w & 1;
  const int d = blockIdx.x;
  const int rt = (d & 7) * 64 + (d >> 6);
  const int ct = (d >> 3) & 7;
  const int b = rt >> 3;
  const int l7 = l & 7, lh = l >> 4, l15 = l & 15;
  const int srow = w * 8 + (l >> 3);
  f32x4 acc[4][4] = {};
  for (int kt = 0; kt < 16; ++kt) {
    const int k0 = kt * 64;
    __syncthreads();
    #pragma unroll
    for (int r = 0; r < 4; ++r) {
      const int row = r * 32 + srow;
      short8 val;
      if constexpr (ACONV) {
        const float* s = (const float*)Asrc + (size_t)(rt * 128 + row) * NE + k0 + l7 * 8;
        val = pack8(*(const float4*)s, *(const float4*)(s + 4));
      } else {
        val = *(const short8*)((const unsigned short*)Asrc + (size_t)(rt * 128 + row) * NE + k0 + l7 * 8);
      }
      *(short8*)(As + row * LDP + l7 * 16) = val;
    }
    #pragma unroll
    for (int r = 0; r < 4; ++r) {
      const int row = r * 32 + srow;
      short8 val;
      if constexpr (BCONV) {
        const float* s = (const float*)Bsrc + (size_t)(ct * 128 + row) * NF + 1024 + k0 + l7 * 8;
        val = pack8(*(const float4*)s, *(const float4*)(s + 4));
      } else {
        val = *(const short8*)((const unsigned short*)Bsrc + (size_t)(ct * 128 + row) * NE + k0 + l7 * 8);
      }
      *(short8*)(Bs + row * LDP + l7 * 16) = val;
    }
    __syncthreads();
    #pragma unroll
    for (int ks = 0; ks < 2; ++ks) {
      bf16x8 af[4], bfr[4];
      const int ku = (ks * 4 + lh) * 16;
      #pragma unroll
      for (int f = 0; f < 4; ++f) {
        af[f]  = *(const bf16x8*)(As + (wr * 64 + f * 16 + l15) * LDP + ku);
        bfr[f] = *(const bf16x8*)(Bs + (wc * 64 + f * 16 + l15) * LDP + ku);
      }
      #pragma unroll
      for (int i = 0; i < 4; ++i)
        #pragma unroll
        for (int jj = 0; jj < 4; ++jj)
          acc[i][jj] = __builtin_amdgcn_mfma_f32_16x16x32_bf16(af[i], bfr[jj], acc[i][jj], 0, 0, 0);
    }
  }
  const int colb = ct * 128 + wc * 64 + l15;
  float uv[4], vv[4];
  #pragma unroll
  for (int jj = 0; jj < 4; ++jj) {
    const int c = colb + jj * 16;
    uv[jj] = u_[b * NA + c];
    vv[jj] = v_[c];
  }
  #pragma unroll
  for (int i = 0; i < 4; ++i) {
    #pragma unroll
    for (int reg = 0; reg < 4; ++reg) {
      float sacc = 0.f;
      #pragma unroll
      for (int jj = 0; jj < 4; ++jj)
        sacc += tanh_fast(acc[i][jj][reg] + uv[jj]) * vv[jj];
      sacc += __shfl_xor(sacc, 1);
      sacc += __shfl_xor(sacc, 2);
      sacc += __shfl_xor(sacc, 4);
      sacc += __shfl_xor(sacc, 8);
      if (l15 == 0) {
        const int m = rt * 128 + wr * 64 + i * 16 + lh * 4 + reg;
        atomicAdd(&scores[m], sacc);
      }
    }
  }
}

// ---------------- standalone softmax / ctx (tier1/2 fallback) ----------------
__global__ __launch_bounds__(256) void k_softmax(float* __restrict__ sc) {
  const int b = blockIdx.x, t = threadIdx.x;
  float4 x = *(float4*)(sc + b * NS + t * 4);
  float mx = fmaxf(fmaxf(x.x, x.y), fmaxf(x.z, x.w));
  #pragma unroll
  for (int m = 1; m < 64; m <<= 1) mx = fmaxf(mx, __shfl_xor(mx, m));
  __shared__ float rmax[4], rsum[4];
  if ((t & 63) == 0) rmax[t >> 6] = mx;
  __syncthreads();
  mx = fmaxf(fmaxf(rmax[0], rmax[1]), fmaxf(rmax[2], rmax[3]));
  float e0 = __expf(x.x - mx), e1 = __expf(x.y - mx);
  float e2 = __expf(x.z - mx), e3 = __expf(x.w - mx);
  float sm = e0 + e1 + e2 + e3;
  #pragma unroll
  for (int m = 1; m < 64; m <<= 1) sm += __shfl_xor(sm, m);
  if ((t & 63) == 0) rsum[t >> 6] = sm;
  __syncthreads();
  sm = rsum[0] + rsum[1] + rsum[2] + rsum[3];
  const float inv = 1.0f / sm;
  float4 o; o.x = e0 * inv; o.y = e1 * inv; o.z = e2 * inv; o.w = e3 * inv;
  *(float4*)(sc + b * NS + t * 4) = o;
}
template <int CONV>
__global__ __launch_bounds__(256) void k_ctx(const void* __restrict__ encsrc,
                                             const float* __restrict__ wgt,
                                             float* __restrict__ ctx) {
  const int b = blockIdx.x >> 4, scn = blockIdx.x & 15;
  const int t = threadIdx.x;
  float a0 = 0.f, a1 = 0.f, a2 = 0.f, a3 = 0.f;
  for (int s = scn * 64; s < scn * 64 + 64; ++s) {
    const float wv = wgt[b * NS + s];
    const size_t base = ((size_t)(b * NS + s)) * NE + t * 4;
    if constexpr (CONV) {
      float4 x = *((const float4*)((const float*)encsrc + base));
      a0 += wv * x.x; a1 += wv * x.y; a2 += wv * x.z; a3 += wv * x.w;
    } else {
      short4v hv = *(const short4v*)((const unsigned short*)encsrc + base);
      a0 += wv * bf2f((unsigned short)hv[0]);
      a1 += wv * bf2f((unsigned short)hv[1]);
      a2 += wv * bf2f((unsigned short)hv[2]);
      a3 += wv * bf2f((unsigned short)hv[3]);
    }
  }
  float* c = ctx + b * NE + t * 4;
  atomicAdd(c + 0, a0); atomicAdd(c + 1, a1);
  atomicAdd(c + 2, a2); atomicAdd(c + 3, a3);
}

// ---------------- ctx f32 -> f32 output (reference output dtype is float32) ----------------
__global__ __launch_bounds__(256) void k_out(const float* __restrict__ ctx,
                                             float* __restrict__ out) {
  const int i = blockIdx.x * 256 + threadIdx.x;
  float4 x = *(const float4*)(ctx + i * 4);
  *(float4*)(out + i * 4) = x;
}

extern "C" void kernel_launch(void* const* d_in, const int* in_sizes, int n_in,
                              void* d_out, int out_size, void* d_ws, size_t ws_size,
                              hipStream_t stream) {
  const float* hidden = (const float*)d_in[0];
  const float* enc    = (const float*)d_in[1];
  const float* W      = (const float*)d_in[2];
  const float* bias   = (const float*)d_in[3];
  const float* v      = (const float*)d_in[4];
  (void)in_sizes; (void)n_in; (void)out_size;

  char* ws = (char*)d_ws;
  const size_t T0 = (4ull << 20) + (128ull << 20);  // Wb + u/sc/ctx + enc_bf16
  const size_t T1 = (3ull << 20);                   // Wb + u/sc/ctx
  const int tier = (ws_size >= T0) ? 0 : ((ws_size >= T1) ? 1 : 2);

  unsigned short* Wb   = (unsigned short*)ws;
  unsigned short* encb = (unsigned short*)(ws + (4ull << 20));
  float* u_  = (tier < 2) ? (float*)(ws + (2ull << 20)) : (float*)ws;
  float* sc  = u_ + NB * NA;
  float* ctx = sc + NB * NS;

  if (tier == 0) {
    // 4 dispatches total: pre (u|zero|convW|convEnc), GEMM, softmax+ctx, out
    k_pre<<<3200, 256, 0, stream>>>(hidden, W, bias, u_, (float4*)sc,
                                    (short8*)Wb, (const float4*)enc, (short8*)encb);
    k_main256<<<1024, 512, 0, stream>>>(encb, Wb, u_, v, sc);
    k_smctx<<<1024, 256, 0, stream>>>(sc, encb, ctx);
    k_out<<<64, 256, 0, stream>>>(ctx, (float*)d_out);
  } else if (tier == 1) {
    k_u<<<512, 256, 0, stream>>>(hidden, W, bias, u_);
    k_zero<<<128, 256, 0, stream>>>((float4*)sc, (NB * NS + NB * NE) / 4);
    k_conv_w<<<512, 256, 0, stream>>>(W, (short8*)Wb);
    k_main_rs<1, 0><<<4096, 256, 0, stream>>>(enc, Wb, u_, v, sc);
    k_softmax<<<64, 256, 0, stream>>>(sc);
    k_ctx<1><<<1024, 256, 0, stream>>>(enc, sc, ctx);
    k_out<<<64, 256, 0, stream>>>(ctx, (float*)d_out);
  } else {
    k_u<<<512, 256, 0, stream>>>(hidden, W, bias, u_);
    k_zero<<<128, 256, 0, stream>>>((float4*)sc, (NB * NS + NB * NE) / 4);
    k_main_rs<1, 1><<<4096, 256, 0, stream>>>(enc, W, u_, v, sc);
    k_softmax<<<64, 256, 0, stream>>>(sc);
    k_ctx<1><<<1024, 256, 0, stream>>>(enc, sc, ctx);
    k_out<<<64, 256, 0, stream>>>(ctx, (float*)d_out);
  }
}

// Round 17
// 250.659 us; speedup vs baseline: 1.5822x; 1.0107x over previous
//
#include <hip/hip_runtime.h>
#include <hip/hip_bf16.h>
#include <stdint.h>

// Problem constants (Attention_21552145891894): B=64, S=1024, DEC=ENC=ATTN=1024
#define NB 64
#define NS 1024
#define NE 1024   // ENC (= K of big GEMM)
#define NA 1024   // ATTN (= N of big GEMM)
#define NF 2048   // DEC+ENC (W_attn row length)
#define LDP 144   // padded LDS row stride (fallback reg-staged kernel only)

typedef __attribute__((ext_vector_type(8))) short   short8;
typedef __attribute__((ext_vector_type(4))) short   short4v;
typedef __attribute__((ext_vector_type(4))) float   f32x4;
typedef __attribute__((ext_vector_type(8))) __bf16  bf16x8;

__device__ __forceinline__ unsigned short f2bf(float x) {
  union { float f; unsigned u; } v; v.f = x;
  unsigned r = v.u + 0x7fffu + ((v.u >> 16) & 1u);   // RNE
  return (unsigned short)(r >> 16);
}
__device__ __forceinline__ float bf2f(unsigned short h) {
  union { unsigned u; float f; } v; v.u = ((unsigned)h) << 16;
  return v.f;
}
__device__ __forceinline__ float tanh_fast(float x) {
  float e = __expf(2.0f * x);                        // overflow -> inf -> 1; underflow -> -1
  return 1.0f - __fdividef(2.0f, e + 1.0f);
}
__device__ __forceinline__ short8 pack8(float4 a, float4 b) {
  short8 h;
  h[0]=(short)f2bf(a.x); h[1]=(short)f2bf(a.y); h[2]=(short)f2bf(a.z); h[3]=(short)f2bf(a.w);
  h[4]=(short)f2bf(b.x); h[5]=(short)f2bf(b.y); h[6]=(short)f2bf(b.z); h[7]=(short)f2bf(b.w);
  return h;
}
__device__ __forceinline__ void gload_lds16(const void* g, void* l) {
  // HW: LDS dest is wave-uniform base + lane*16; size must be literal 16 (m97/m104)
  __builtin_amdgcn_global_load_lds((const __attribute__((address_space(1))) void*)g,
                                   (__attribute__((address_space(3))) void*)l, 16, 0, 0);
}

// ======== fused pre-pass (tier0): k_u | zero(sc,out) | conv_w | conv_enc ========
// All sub-kernels mutually independent; block-range dispatch, per-block uniform
// branch. Zeroes BOTH sc and d_out every call (determinism across graph replays);
// k_smctx then accumulates directly into d_out (k_out eliminated).
__global__ __launch_bounds__(256) void k_pre(const float* __restrict__ hidden,
                                             const float* __restrict__ W,
                                             const float* __restrict__ bias,
                                             float* __restrict__ u_,
                                             float4* __restrict__ scz,
                                             float4* __restrict__ outz,
                                             short8* __restrict__ Wb,
                                             const float4* __restrict__ encf,
                                             short8* __restrict__ encb) {
  const int bid = blockIdx.x;
  const int tid = threadIdx.x;
  if (bid < 512) {
    // ---- k_u: u[b,a] = hidden[b] . W[a,0:1024] + bias[a] (fp32 exact) ----
    const int l = tid & 63;
    const int w = tid >> 6;
    const int a = (bid >> 1) * 4 + w;
    const int bh = bid & 1;
    const float* wrow = W + (size_t)a * NF;
    float4 wv[4];
    #pragma unroll
    for (int i = 0; i < 4; ++i) wv[i] = *(const float4*)(wrow + l * 4 + i * 256);
    const float ba = bias[a];
    for (int b = bh * 32; b < bh * 32 + 32; ++b) {
      const float* hrow = hidden + b * 1024;
      float s = 0.f;
      #pragma unroll
      for (int i = 0; i < 4; ++i) {
        float4 hv = *(const float4*)(hrow + l * 4 + i * 256);
        s += wv[i].x * hv.x + wv[i].y * hv.y + wv[i].z * hv.z + wv[i].w * hv.w;
      }
      #pragma unroll
      for (int m = 1; m < 64; m <<= 1) s += __shfl_xor(s, m);
      if (l == 0) u_[b * NA + a] = s + ba;
    }
  } else if (bid < 640) {
    // ---- zero: sc (16384 float4) then d_out (16384 float4) ----
    const int i = (bid - 512) * 256 + tid;
    float4 z; z.x = z.y = z.z = z.w = 0.f;
    if (i < 16384) scz[i] = z;
    else           outz[i - 16384] = z;
  } else if (bid < 1152) {
    // ---- conv_w: W_enc f32 -> bf16 [1024][1024] ----
    const int id = (bid - 640) * 256 + tid;
    const int a = id >> 7, ku = id & 127;
    const float* s = W + (size_t)a * NF + 1024 + ku * 8;
    Wb[id] = pack8(*(const float4*)s, *(const float4*)(s + 4));
  } else {
    // ---- conv_enc: enc f32 -> bf16 (grid-stride, 2048 blocks) ----
    const int n8 = NB * NS * NE / 8;
    int i = (bid - 1152) * 256 + tid;
    const int stride = 2048 * 256;
    for (; i < n8; i += stride) {
      float4 a = encf[2 * i], b = encf[2 * i + 1];
      encb[i] = pack8(a, b);
    }
  }
}

// ---------------- standalone versions (tier1/2 fallback paths) ----------------
__global__ __launch_bounds__(256) void k_zero(float4* __restrict__ p, int n4) {
  int i = blockIdx.x * 256 + threadIdx.x;
  if (i < n4) { float4 z; z.x = z.y = z.z = z.w = 0.f; p[i] = z; }
}
__global__ __launch_bounds__(256) void k_conv_w(const float* __restrict__ W, short8* __restrict__ dst) {
  const int id = blockIdx.x * 256 + threadIdx.x;
  const int a = id >> 7, ku = id & 127;
  const float* s = W + (size_t)a * NF + 1024 + ku * 8;
  dst[id] = pack8(*(const float4*)s, *(const float4*)(s + 4));
}
__global__ __launch_bounds__(256) void k_u(const float* __restrict__ hidden,
                                           const float* __restrict__ W,
                                           const float* __restrict__ bias,
                                           float* __restrict__ u) {
  const int l = threadIdx.x & 63;
  const int w = threadIdx.x >> 6;
  const int a = (blockIdx.x >> 1) * 4 + w;
  const int bh = blockIdx.x & 1;
  const float* wrow = W + (size_t)a * NF;
  float4 wv[4];
  #pragma unroll
  for (int i = 0; i < 4; ++i) wv[i] = *(const float4*)(wrow + l * 4 + i * 256);
  const float ba = bias[a];
  for (int b = bh * 32; b < bh * 32 + 32; ++b) {
    const float* hrow = hidden + b * 1024;
    float s = 0.f;
    #pragma unroll
    for (int i = 0; i < 4; ++i) {
      float4 hv = *(const float4*)(hrow + l * 4 + i * 256);
      s += wv[i].x * hv.x + wv[i].y * hv.y + wv[i].z * hv.z + wv[i].w * hv.w;
    }
    #pragma unroll
    for (int m = 1; m < 64; m <<= 1) s += __shfl_xor(s, m);
    if (l == 0) u[b * NA + a] = s + ba;
  }
}

// ======== main fused GEMM (tier0): 256x256 tile, double-buffered, 1 barrier/K-tile ========
// Round-7/15/16 verified optimum (193us, 712 TF, MfmaUtil 30%) — best of 7 structural
// variants; at the reproducible-structure ceiling. UNCHANGED.
__global__ __launch_bounds__(512, 2) void k_main256(const unsigned short* __restrict__ Ab,
                                                    const unsigned short* __restrict__ Bb,
                                                    const float* __restrict__ u_,
                                                    const float* __restrict__ v_,
                                                    float* __restrict__ scores) {
  __shared__ __align__(16) char smem[2 * 65536];

  const int tid = threadIdx.x;
  const int l = tid & 63;
  const int w = tid >> 6;                   // 0..7
  const int wr = w >> 2, wc = w & 3;        // 2M x 4N wave grid
  const int d = blockIdx.x;
  const int xcd = d & 7, q = d >> 3;
  const int rt = xcd * 32 + (q >> 2);       // row tile [0,256)
  const int ct = q & 3;                     // col tile [0,4)
  const int b = rt >> 2;                    // batch (256-row tiles never straddle)
  const int lh = l >> 4, l15 = l & 15, l7 = l & 7;

  const int ssk = ((tid & 7) ^ ((tid >> 3) & 7)) * 8;
  const unsigned short* aS = Ab + (size_t)(rt * 256 + (tid >> 3)) * NE + ssk;
  const unsigned short* bS = Bb + (size_t)(ct * 256 + (tid >> 3)) * NE + ssk;
  const int wdst = w * 1024;                // wave-uniform LDS dest offset

  f32x4 acc[8][4] = {};

#define STAGE256(tt) do { \
    char* dst_ = smem + (((tt) & 1) << 16); \
    const unsigned short* a_ = aS + (size_t)(tt) * 64; \
    const unsigned short* b_ = bS + (size_t)(tt) * 64; \
    gload_lds16(a_,                    dst_ + wdst); \
    gload_lds16(a_ + (size_t) 64 * NE, dst_ +  64 * 128 + wdst); \
    gload_lds16(a_ + (size_t)128 * NE, dst_ + 128 * 128 + wdst); \
    gload_lds16(a_ + (size_t)192 * NE, dst_ + 192 * 128 + wdst); \
    gload_lds16(b_,                    dst_ + 32768 + wdst); \
    gload_lds16(b_ + (size_t) 64 * NE, dst_ + 32768 +  64 * 128 + wdst); \
    gload_lds16(b_ + (size_t)128 * NE, dst_ + 32768 + 128 * 128 + wdst); \
    gload_lds16(b_ + (size_t)192 * NE, dst_ + 32768 + 192 * 128 + wdst); } while (0)

  STAGE256(0);                              // prologue: tile 0 into buf 0

  for (int t = 0; t < 16; ++t) {
    asm volatile("s_waitcnt vmcnt(0)" ::: "memory");   // tile t certified (aged 1 tile)
    asm volatile("s_barrier" ::: "memory");            // buf (t+1)&1 free of readers
    if (t < 15) STAGE256(t + 1);                       // overlaps with compute below

    const char* As = smem + ((t & 1) << 16);
    const char* Bs = As + 32768;

    bf16x8 areg[8][2];
    #pragma unroll
    for (int rf = 0; rf < 8; ++rf)
      #pragma unroll
      for (int kh = 0; kh < 2; ++kh)
        areg[rf][kh] = *(const bf16x8*)(As + (wr * 128 + rf * 16 + l15) * 128
                                           + (((kh * 4 + lh) ^ l7) << 4));
    #pragma unroll
    for (int cfh = 0; cfh < 2; ++cfh) {
      bf16x8 breg[2][2];
      #pragma unroll
      for (int c2 = 0; c2 < 2; ++c2)
        #pragma unroll
        for (int kh = 0; kh < 2; ++kh)
          breg[c2][kh] = *(const bf16x8*)(Bs + (wc * 64 + (cfh * 2 + c2) * 16 + l15) * 128
                                             + (((kh * 4 + lh) ^ l7) << 4));
      __builtin_amdgcn_s_setprio(1);
      #pragma unroll
      for (int rf = 0; rf < 8; ++rf)
        #pragma unroll
        for (int c2 = 0; c2 < 2; ++c2)
          #pragma unroll
          for (int kh = 0; kh < 2; ++kh)
            acc[rf][cfh * 2 + c2] = __builtin_amdgcn_mfma_f32_16x16x32_bf16(
                areg[rf][kh], breg[c2][kh], acc[rf][cfh * 2 + c2], 0, 0, 0);
      __builtin_amdgcn_s_setprio(0);
    }
  }
#undef STAGE256

  // ---- epilogue: D frag col=l&15, row=(l>>4)*4+reg (m89-verified) ----
  const int colb = ct * 256 + wc * 64 + l15;
  float uv[4], vv[4];
  #pragma unroll
  for (int cf = 0; cf < 4; ++cf) {
    const int c = colb + cf * 16;
    uv[cf] = u_[b * NA + c];
    vv[cf] = v_[c];
  }
  #pragma unroll
  for (int rf = 0; rf < 8; ++rf) {
    #pragma unroll
    for (int reg = 0; reg < 4; ++reg) {
      float sacc = 0.f;
      #pragma unroll
      for (int cf = 0; cf < 4; ++cf)
        sacc += tanh_fast(acc[rf][cf][reg] + uv[cf]) * vv[cf];
      sacc += __shfl_xor(sacc, 1);
      sacc += __shfl_xor(sacc, 2);
      sacc += __shfl_xor(sacc, 4);
      sacc += __shfl_xor(sacc, 8);
      if (l15 == 0) {
        const int m = rt * 256 + wr * 128 + rf * 16 + lh * 4 + reg;
        atomicAdd(&scores[m], sacc);         // 16 partials per row (4 ct x 4 wc)
      }
    }
  }
}

// ======== fused softmax+context (tier0): accumulates DIRECTLY into d_out ========
// Each of the 16 blocks per batch recomputes the row softmax (reduction replicated
// op-for-op from k_softmax -> bit-identical weights), stores w in LDS, then runs
// its context chunk, atomicAdd into d_out (zeroed by k_pre each call).
__global__ __launch_bounds__(256) void k_smctx(const float* __restrict__ sc,
                                               const unsigned short* __restrict__ encb,
                                               float* __restrict__ out) {
  const int b = blockIdx.x >> 4, scn = blockIdx.x & 15;
  const int t = threadIdx.x;
  __shared__ float rmax[4], rsum[4];
  __shared__ float wbuf[NS];

  float4 x = *(const float4*)(sc + b * NS + t * 4);
  float mx = fmaxf(fmaxf(x.x, x.y), fmaxf(x.z, x.w));
  #pragma unroll
  for (int m = 1; m < 64; m <<= 1) mx = fmaxf(mx, __shfl_xor(mx, m));
  if ((t & 63) == 0) rmax[t >> 6] = mx;
  __syncthreads();
  mx = fmaxf(fmaxf(rmax[0], rmax[1]), fmaxf(rmax[2], rmax[3]));
  float e0 = __expf(x.x - mx), e1 = __expf(x.y - mx);
  float e2 = __expf(x.z - mx), e3 = __expf(x.w - mx);
  float sm = e0 + e1 + e2 + e3;
  #pragma unroll
  for (int m = 1; m < 64; m <<= 1) sm += __shfl_xor(sm, m);
  if ((t & 63) == 0) rsum[t >> 6] = sm;
  __syncthreads();
  sm = rsum[0] + rsum[1] + rsum[2] + rsum[3];
  const float inv = 1.0f / sm;
  wbuf[t * 4 + 0] = e0 * inv;
  wbuf[t * 4 + 1] = e1 * inv;
  wbuf[t * 4 + 2] = e2 * inv;
  wbuf[t * 4 + 3] = e3 * inv;
  __syncthreads();

  float a0 = 0.f, a1 = 0.f, a2 = 0.f, a3 = 0.f;
  for (int s = scn * 64; s < scn * 64 + 64; ++s) {
    const float wv = wbuf[s];
    const size_t base = ((size_t)(b * NS + s)) * NE + t * 4;
    short4v hv = *(const short4v*)(encb + base);
    a0 += wv * bf2f((unsigned short)hv[0]);
    a1 += wv * bf2f((unsigned short)hv[1]);
    a2 += wv * bf2f((unsigned short)hv[2]);
    a3 += wv * bf2f((unsigned short)hv[3]);
  }
  float* c = out + b * NE + t * 4;
  atomicAdd(c + 0, a0); atomicAdd(c + 1, a1);
  atomicAdd(c + 2, a2); atomicAdd(c + 3, a3);
}

// ======== fallback (small ws): reg-staged padded-LDS version (round-3-verified) ========
template <int ACONV, int BCONV>
__global__ __launch_bounds__(256) void k_main_rs(const void* __restrict__ Asrc,
                                                 const void* __restrict__ Bsrc,
                                                 const float* __restrict__ u_,
                                                 const float* __restrict__ v_,
                                                 float* __restrict__ scores) {
  __shared__ __align__(16) char smemf[2 * 128 * LDP];
  char* As = smemf;
  char* Bs = smemf + 128 * LDP;
  const int tid = threadIdx.x;
  const int l = tid & 63;
  const int w = tid >> 6;
  const int wr = w >> 1, wc = w & 1;
  const int d = blockIdx.x;
  const int rt = (d & 7) * 64 + (d >> 6);
  const int ct = (d >> 3) & 7;
  const int b = rt >> 3;
  const int l7 = l & 7, lh = l >> 4, l15 = l & 15;
  const int srow = w * 8 + (l >> 3);
  f32x4 acc[4][4] = {};
  for (int kt = 0; kt < 16; ++kt) {
    const int k0 = kt * 64;
    __syncthreads();
    #pragma unroll
    for (int r = 0; r < 4; ++r) {
      const int row = r * 32 + srow;
      short8 val;
      if constexpr (ACONV) {
        const float* s = (const float*)Asrc + (size_t)(rt * 128 + row) * NE + k0 + l7 * 8;
        val = pack8(*(const float4*)s, *(const float4*)(s + 4));
      } else {
        val = *(const short8*)((const unsigned short*)Asrc + (size_t)(rt * 128 + row) * NE + k0 + l7 * 8);
      }
      *(short8*)(As + row * LDP + l7 * 16) = val;
    }
    #pragma unroll
    for (int r = 0; r < 4; ++r) {
      const int row = r * 32 + srow;
      short8 val;
      if constexpr (BCONV) {
        const float* s = (const float*)Bsrc + (size_t)(ct * 128 + row) * NF + 1024 + k0 + l7 * 8;
        val = pack8(*(const float4*)s, *(const float4*)(s + 4));
      } else {
        val = *(const short8*)((const unsigned short*)Bsrc + (size_t)(ct * 128 + row) * NE + k0 + l7 * 8);
      }
      *(short8*)(Bs + row * LDP + l7 * 16) = val;
    }
    __syncthreads();
    #pragma unroll
    for (int ks = 0; ks < 2; ++ks) {
      bf16x8 af[4], bfr[4];
      const int ku = (ks * 4 + lh) * 16;
      #pragma unroll
      for (int f = 0; f < 4; ++f) {
        af[f]  = *(const bf16x8*)(As + (wr * 64 + f * 16 + l15) * LDP + ku);
        bfr[f] = *(const bf16x8*)(Bs + (wc * 64 + f * 16 + l15) * LDP + ku);
      }
      #pragma unroll
      for (int i = 0; i < 4; ++i)
        #pragma unroll
        for (int jj = 0; jj < 4; ++jj)
          acc[i][jj] = __builtin_amdgcn_mfma_f32_16x16x32_bf16(af[i], bfr[jj], acc[i][jj], 0, 0, 0);
    }
  }
  const int colb = ct * 128 + wc * 64 + l15;
  float uv[4], vv[4];
  #pragma unroll
  for (int jj = 0; jj < 4; ++jj) {
    const int c = colb + jj * 16;
    uv[jj] = u_[b * NA + c];
    vv[jj] = v_[c];
  }
  #pragma unroll
  for (int i = 0; i < 4; ++i) {
    #pragma unroll
    for (int reg = 0; reg < 4; ++reg) {
      float sacc = 0.f;
      #pragma unroll
      for (int jj = 0; jj < 4; ++jj)
        sacc += tanh_fast(acc[i][jj][reg] + uv[jj]) * vv[jj];
      sacc += __shfl_xor(sacc, 1);
      sacc += __shfl_xor(sacc, 2);
      sacc += __shfl_xor(sacc, 4);
      sacc += __shfl_xor(sacc, 8);
      if (l15 == 0) {
        const int m = rt * 128 + wr * 64 + i * 16 + lh * 4 + reg;
        atomicAdd(&scores[m], sacc);
      }
    }
  }
}

// ---------------- standalone softmax / ctx / out (tier1/2 fallback) ----------------
__global__ __launch_bounds__(256) void k_softmax(float* __restrict__ sc) {
  const int b = blockIdx.x, t = threadIdx.x;
  float4 x = *(float4*)(sc + b * NS + t * 4);
  float mx = fmaxf(fmaxf(x.x, x.y), fmaxf(x.z, x.w));
  #pragma unroll
  for (int m = 1; m < 64; m <<= 1) mx = fmaxf(mx, __shfl_xor(mx, m));
  __shared__ float rmax[4], rsum[4];
  if ((t & 63) == 0) rmax[t >> 6] = mx;
  __syncthreads();
  mx = fmaxf(fmaxf(rmax[0], rmax[1]), fmaxf(rmax[2], rmax[3]));
  float e0 = __expf(x.x - mx), e1 = __expf(x.y - mx);
  float e2 = __expf(x.z - mx), e3 = __expf(x.w - mx);
  float sm = e0 + e1 + e2 + e3;
  #pragma unroll
  for (int m = 1; m < 64; m <<= 1) sm += __shfl_xor(sm, m);
  if ((t & 63) == 0) rsum[t >> 6] = sm;
  __syncthreads();
  sm = rsum[0] + rsum[1] + rsum[2] + rsum[3];
  const float inv = 1.0f / sm;
  float4 o; o.x = e0 * inv; o.y = e1 * inv; o.z = e2 * inv; o.w = e3 * inv;
  *(float4*)(sc + b * NS + t * 4) = o;
}
template <int CONV>
__global__ __launch_bounds__(256) void k_ctx(const void* __restrict__ encsrc,
                                             const float* __restrict__ wgt,
                                             float* __restrict__ ctx) {
  const int b = blockIdx.x >> 4, scn = blockIdx.x & 15;
  const int t = threadIdx.x;
  float a0 = 0.f, a1 = 0.f, a2 = 0.f, a3 = 0.f;
  for (int s = scn * 64; s < scn * 64 + 64; ++s) {
    const float wv = wgt[b * NS + s];
    const size_t base = ((size_t)(b * NS + s)) * NE + t * 4;
    if constexpr (CONV) {
      float4 x = *((const float4*)((const float*)encsrc + base));
      a0 += wv * x.x; a1 += wv * x.y; a2 += wv * x.z; a3 += wv * x.w;
    } else {
      short4v hv = *(const short4v*)((const unsigned short*)encsrc + base);
      a0 += wv * bf2f((unsigned short)hv[0]);
      a1 += wv * bf2f((unsigned short)hv[1]);
      a2 += wv * bf2f((unsigned short)hv[2]);
      a3 += wv * bf2f((unsigned short)hv[3]);
    }
  }
  float* c = ctx + b * NE + t * 4;
  atomicAdd(c + 0, a0); atomicAdd(c + 1, a1);
  atomicAdd(c + 2, a2); atomicAdd(c + 3, a3);
}
__global__ __launch_bounds__(256) void k_out(const float* __restrict__ ctx,
                                             float* __restrict__ out) {
  const int i = blockIdx.x * 256 + threadIdx.x;
  float4 x = *(const float4*)(ctx + i * 4);
  *(float4*)(out + i * 4) = x;
}

extern "C" void kernel_launch(void* const* d_in, const int* in_sizes, int n_in,
                              void* d_out, int out_size, void* d_ws, size_t ws_size,
                              hipStream_t stream) {
  const float* hidden = (const float*)d_in[0];
  const float* enc    = (const float*)d_in[1];
  const float* W      = (const float*)d_in[2];
  const float* bias   = (const float*)d_in[3];
  const float* v      = (const float*)d_in[4];
  (void)in_sizes; (void)n_in; (void)out_size;

  char* ws = (char*)d_ws;
  const size_t T0 = (4ull << 20) + (128ull << 20);  // Wb + u/sc/ctx + enc_bf16
  const size_t T1 = (3ull << 20);                   // Wb + u/sc/ctx
  const int tier = (ws_size >= T0) ? 0 : ((ws_size >= T1) ? 1 : 2);

  unsigned short* Wb   = (unsigned short*)ws;
  unsigned short* encb = (unsigned short*)(ws + (4ull << 20));
  float* u_  = (tier < 2) ? (float*)(ws + (2ull << 20)) : (float*)ws;
  float* sc  = u_ + NB * NA;
  float* ctx = sc + NB * NS;

  if (tier == 0) {
    // 3 dispatches: pre (u | zero sc+out | convW | convEnc), GEMM, softmax+ctx->out
    k_pre<<<3200, 256, 0, stream>>>(hidden, W, bias, u_, (float4*)sc, (float4*)d_out,
                                    (short8*)Wb, (const float4*)enc, (short8*)encb);
    k_main256<<<1024, 512, 0, stream>>>(encb, Wb, u_, v, sc);
    k_smctx<<<1024, 256, 0, stream>>>(sc, encb, (float*)d_out);
  } else if (tier == 1) {
    k_u<<<512, 256, 0, stream>>>(hidden, W, bias, u_);
    k_zero<<<128, 256, 0, stream>>>((float4*)sc, (NB * NS + NB * NE) / 4);
    k_conv_w<<<512, 256, 0, stream>>>(W, (short8*)Wb);
    k_main_rs<1, 0><<<4096, 256, 0, stream>>>(enc, Wb, u_, v, sc);
    k_softmax<<<64, 256, 0, stream>>>(sc);
    k_ctx<1><<<1024, 256, 0, stream>>>(enc, sc, ctx);
    k_out<<<64, 256, 0, stream>>>(ctx, (float*)d_out);
  } else {
    k_u<<<512, 256, 0, stream>>>(hidden, W, bias, u_);
    k_zero<<<128, 256, 0, stream>>>((float4*)sc, (NB * NS + NB * NE) / 4);
    k_main_rs<1, 1><<<4096, 256, 0, stream>>>(enc, W, u_, v, sc);
    k_softmax<<<64, 256, 0, stream>>>(sc);
    k_ctx<1><<<1024, 256, 0, stream>>>(enc, sc, ctx);
    k_out<<<64, 256, 0, stream>>>(ctx, (float*)d_out);
  }
}